// Round 3
// baseline (337.703 us; speedup 1.0000x reference)
//
#include <hip/hip_runtime.h>
#include <hip/hip_fp16.h>
#include <hip/hip_cooperative_groups.h>

namespace cg = cooperative_groups;

#define TP_ 4
#define TOKENS_ 8192
#define HIDDEN_ 4096
#define EPS_ 1e-6f
#define FP8MAX_ 448.0f

static constexpr size_t NELEM = (size_t)TOKENS_ * HIDDEN_;  // 33,554,432
static constexpr size_t WS_AMAX_BYTES = 16;
static constexpr size_t WS_NEEDED = WS_AMAX_BYTES + NELEM * sizeof(unsigned short);

static __device__ inline unsigned int pack_half2(float a, float b) {
    __half2 h = __floats2half2_rn(a, b);
    return *reinterpret_cast<unsigned int*>(&h);
}

// ---------------- cooperative single-pass kernel ----------------
// 1024 blocks x 256 threads, 4 blocks/CU (co-resident). Each block owns 8
// rows; each thread holds 8 rows x 16 floats = 128 normed values, fp16-packed
// into 64 VGPRs, across a grid sync. Phase 1: all-reduce + RMSNorm + amax.
// Phase 2: read global amax, scale+clip, store fp32 q from registers.
__global__ __launch_bounds__(256, 4) void k_coop(
    const float* __restrict__ hs, const float* __restrict__ w,
    float* __restrict__ q_out, float* __restrict__ scale_out,
    unsigned int* __restrict__ amax_bits)
{
    const int tid = threadIdx.x;
    const int wave = tid >> 6;
    const int row0 = blockIdx.x * 8;
    const size_t S4 = NELEM / 4;  // shard stride in float4 units
    const float4* __restrict__ w4 = reinterpret_cast<const float4*>(w);

    unsigned int packed[64];  // [row r][j][2] -> r*8 + j*2 + {0,1}
    float bmax = 0.f;
    __shared__ float red[4];

#pragma unroll
    for (int r = 0; r < 8; ++r) {
        const int row = row0 + r;
        const float4* __restrict__ base =
            reinterpret_cast<const float4*>(hs) + (size_t)row * (HIDDEN_ / 4);
        float4 sv[4];
        float ss = 0.f;
#pragma unroll
        for (int j = 0; j < 4; ++j) {
            const size_t idx = (size_t)tid + j * 256;
            float4 a = base[idx];
            float4 b = base[idx + S4];
            float4 c = base[idx + 2 * S4];
            float4 d = base[idx + 3 * S4];
            float4 s;
            s.x = (a.x + b.x) + (c.x + d.x);
            s.y = (a.y + b.y) + (c.y + d.y);
            s.z = (a.z + b.z) + (c.z + d.z);
            s.w = (a.w + b.w) + (c.w + d.w);
            sv[j] = s;
            ss += s.x * s.x + s.y * s.y + s.z * s.z + s.w * s.w;
        }
#pragma unroll
        for (int off = 32; off > 0; off >>= 1) ss += __shfl_down(ss, off, 64);
        if ((tid & 63) == 0) red[wave] = ss;
        __syncthreads();
        ss = red[0] + red[1] + red[2] + red[3];
        const float inv = rsqrtf(ss * (1.0f / HIDDEN_) + EPS_);
#pragma unroll
        for (int j = 0; j < 4; ++j) {
            float4 wv = w4[(size_t)tid + j * 256];
            float4 s = sv[j];
            float4 o;
            o.x = s.x * inv * wv.x;
            o.y = s.y * inv * wv.y;
            o.z = s.z * inv * wv.z;
            o.w = s.w * inv * wv.w;
            packed[r * 8 + j * 2]     = pack_half2(o.x, o.y);
            packed[r * 8 + j * 2 + 1] = pack_half2(o.z, o.w);
            bmax = fmaxf(bmax, fmaxf(fmaxf(fabsf(o.x), fabsf(o.y)),
                                     fmaxf(fabsf(o.z), fabsf(o.w))));
        }
        __syncthreads();  // protect red[] for next row
    }

    // block max -> one device atomic
#pragma unroll
    for (int off = 32; off > 0; off >>= 1)
        bmax = fmaxf(bmax, __shfl_down(bmax, off, 64));
    if ((tid & 63) == 0) red[wave] = bmax;
    __syncthreads();
    if (tid == 0) {
        bmax = fmaxf(fmaxf(red[0], red[1]), fmaxf(red[2], red[3]));
        atomicMax(amax_bits, __float_as_uint(bmax));  // values >= 0
    }

    cg::this_grid().sync();

    const float amax = __uint_as_float(
        *reinterpret_cast<volatile unsigned int*>(amax_bits));
    const float scale = fmaxf(amax, 1e-12f) / FP8MAX_;
    const float invs = 1.0f / scale;

#pragma unroll
    for (int r = 0; r < 8; ++r) {
        const int row = row0 + r;
        float4* __restrict__ dst =
            reinterpret_cast<float4*>(q_out) + (size_t)row * (HIDDEN_ / 4);
#pragma unroll
        for (int j = 0; j < 4; ++j) {
            float2 f0 = __half22float2(
                *reinterpret_cast<__half2*>(&packed[r * 8 + j * 2]));
            float2 f1 = __half22float2(
                *reinterpret_cast<__half2*>(&packed[r * 8 + j * 2 + 1]));
            float4 o;
            o.x = fminf(fmaxf(f0.x * invs, -FP8MAX_), FP8MAX_);
            o.y = fminf(fmaxf(f0.y * invs, -FP8MAX_), FP8MAX_);
            o.z = fminf(fmaxf(f1.x * invs, -FP8MAX_), FP8MAX_);
            o.w = fminf(fmaxf(f1.y * invs, -FP8MAX_), FP8MAX_);
            dst[(size_t)tid + j * 256] = o;
        }
    }
    if (blockIdx.x == 0 && tid == 0) scale_out[0] = scale;
}

// ---------------- fallback: two-pass fp16-intermediate (proven, R2) --------

__global__ __launch_bounds__(256) void k_norm_h(
    const float* __restrict__ hs, const float* __restrict__ w,
    unsigned int* __restrict__ normed_h2, unsigned int* __restrict__ amax_bits)
{
    const int row = blockIdx.x;
    const int tid = threadIdx.x;
    const size_t S4 = NELEM / 4;
    const float4* __restrict__ base =
        reinterpret_cast<const float4*>(hs) + (size_t)row * (HIDDEN_ / 4);
    const float4* __restrict__ w4 = reinterpret_cast<const float4*>(w);

    float4 sv[4];
    float ss = 0.f;
#pragma unroll
    for (int j = 0; j < 4; ++j) {
        const size_t idx = (size_t)tid + j * 256;
        float4 a = base[idx];
        float4 b = base[idx + S4];
        float4 c = base[idx + 2 * S4];
        float4 d = base[idx + 3 * S4];
        float4 s;
        s.x = (a.x + b.x) + (c.x + d.x);
        s.y = (a.y + b.y) + (c.y + d.y);
        s.z = (a.z + b.z) + (c.z + d.z);
        s.w = (a.w + b.w) + (c.w + d.w);
        sv[j] = s;
        ss += s.x * s.x + s.y * s.y + s.z * s.z + s.w * s.w;
    }
    __shared__ float red[4];
#pragma unroll
    for (int off = 32; off > 0; off >>= 1) ss += __shfl_down(ss, off, 64);
    const int wave = tid >> 6;
    if ((tid & 63) == 0) red[wave] = ss;
    __syncthreads();
    ss = red[0] + red[1] + red[2] + red[3];
    const float inv = rsqrtf(ss * (1.0f / HIDDEN_) + EPS_);

    uint2* __restrict__ out =
        reinterpret_cast<uint2*>(normed_h2) + (size_t)row * (HIDDEN_ / 4);
    float am = 0.f;
#pragma unroll
    for (int j = 0; j < 4; ++j) {
        const size_t idx = (size_t)tid + j * 256;
        float4 wv = w4[idx];
        float4 s = sv[j];
        float4 o;
        o.x = s.x * inv * wv.x;
        o.y = s.y * inv * wv.y;
        o.z = s.z * inv * wv.z;
        o.w = s.w * inv * wv.w;
        uint2 p;
        p.x = pack_half2(o.x, o.y);
        p.y = pack_half2(o.z, o.w);
        out[idx] = p;
        am = fmaxf(am, fmaxf(fmaxf(fabsf(o.x), fabsf(o.y)),
                             fmaxf(fabsf(o.z), fabsf(o.w))));
    }
    __shared__ float redm[4];
#pragma unroll
    for (int off = 32; off > 0; off >>= 1)
        am = fmaxf(am, __shfl_down(am, off, 64));
    if ((tid & 63) == 0) redm[wave] = am;
    __syncthreads();
    if (tid == 0) {
        am = fmaxf(fmaxf(redm[0], redm[1]), fmaxf(redm[2], redm[3]));
        atomicMax(amax_bits, __float_as_uint(am));
    }
}

__global__ __launch_bounds__(256) void k_quant_h(
    const unsigned int* __restrict__ normed_h2,
    const unsigned int* __restrict__ amax_bits,
    float* __restrict__ q_out, float* __restrict__ scale_out)
{
    const float amax = __uint_as_float(*amax_bits);
    const float scale = fmaxf(amax, 1e-12f) / FP8MAX_;
    const float invs = 1.0f / scale;
    const size_t n8 = NELEM / 8;
    const uint4* __restrict__ src = reinterpret_cast<const uint4*>(normed_h2);
    float4* __restrict__ dst = reinterpret_cast<float4*>(q_out);
    const size_t stride = (size_t)gridDim.x * blockDim.x;
    for (size_t i = (size_t)blockIdx.x * blockDim.x + threadIdx.x; i < n8;
         i += stride) {
        uint4 u = src[i];
        float2 f0 = __half22float2(*reinterpret_cast<const __half2*>(&u.x));
        float2 f1 = __half22float2(*reinterpret_cast<const __half2*>(&u.y));
        float2 f2 = __half22float2(*reinterpret_cast<const __half2*>(&u.z));
        float2 f3 = __half22float2(*reinterpret_cast<const __half2*>(&u.w));
        float4 a, b;
        a.x = fminf(fmaxf(f0.x * invs, -FP8MAX_), FP8MAX_);
        a.y = fminf(fmaxf(f0.y * invs, -FP8MAX_), FP8MAX_);
        a.z = fminf(fmaxf(f1.x * invs, -FP8MAX_), FP8MAX_);
        a.w = fminf(fmaxf(f1.y * invs, -FP8MAX_), FP8MAX_);
        b.x = fminf(fmaxf(f2.x * invs, -FP8MAX_), FP8MAX_);
        b.y = fminf(fmaxf(f2.y * invs, -FP8MAX_), FP8MAX_);
        b.z = fminf(fmaxf(f3.x * invs, -FP8MAX_), FP8MAX_);
        b.w = fminf(fmaxf(f3.y * invs, -FP8MAX_), FP8MAX_);
        dst[i * 2] = a;
        dst[i * 2 + 1] = b;
    }
    if (blockIdx.x == 0 && threadIdx.x == 0) scale_out[0] = scale;
}

extern "C" void kernel_launch(void* const* d_in, const int* in_sizes, int n_in,
                              void* d_out, int out_size, void* d_ws, size_t ws_size,
                              hipStream_t stream) {
    const float* hs = (const float*)d_in[0];   // [TP, TOKENS, HIDDEN]
    // d_in[1] = residual: unused by the reference computation
    const float* w  = (const float*)d_in[2];   // [HIDDEN]
    float* out = (float*)d_out;                // [N] q values + [1] scale
    float* scale_out = out + NELEM;
    unsigned int* amax_bits = (unsigned int*)d_ws;

    hipMemsetAsync(d_ws, 0, sizeof(unsigned int), stream);

    void* args[] = {(void*)&hs, (void*)&w, (void*)&out, (void*)&scale_out,
                    (void*)&amax_bits};
    hipError_t err = hipLaunchCooperativeKernel(
        (const void*)k_coop, dim3(1024), dim3(256), args, 0, stream);
    if (err != hipSuccess && ws_size >= WS_NEEDED) {
        // fallback: proven two-pass fp16-intermediate path (~181 us)
        unsigned int* normed_h2 = (unsigned int*)((char*)d_ws + WS_AMAX_BYTES);
        k_norm_h<<<TOKENS_, 256, 0, stream>>>(hs, w, normed_h2, amax_bits);
        k_quant_h<<<2048, 256, 0, stream>>>(normed_h2, amax_bits, out,
                                            scale_out);
    }
}

// Round 5
// 152.209 us; speedup vs baseline: 2.2187x; 2.2187x over previous
//
#include <hip/hip_runtime.h>
#include <hip/hip_fp16.h>

#define TP_ 4
#define TOKENS_ 8192
#define HIDDEN_ 4096
#define EPS_ 1e-6f
#define FP8MAX_ 448.0f

typedef float f32x4 __attribute__((ext_vector_type(4)));
typedef unsigned int u32x4 __attribute__((ext_vector_type(4)));

static constexpr size_t NELEM = (size_t)TOKENS_ * HIDDEN_;  // 33,554,432
// ws layout: [0..4) scale | [4K..4K+32K) bmax[8192] | [64K ...) fp16 buf
static constexpr size_t WS_SCALE_OFF = 0;
static constexpr size_t WS_BMAX_OFF = 4096;
static constexpr size_t WS_H16_OFF = 65536;
static constexpr size_t WS_NEEDED = WS_H16_OFF + NELEM * sizeof(unsigned short);

static __device__ inline unsigned int pack_half2(float a, float b) {
    __half2 h = __floats2half2_rn(a, b);
    return *reinterpret_cast<unsigned int*>(&h);
}

// Pass 1: all-reduce + RMSNorm, one block per row. fp16 normed -> d_ws,
// per-block max -> bmax[row] (no atomics). hs read nontemporal (streaming,
// no reuse) to preserve L2/L3 capacity for the fp16 intermediate.
__global__ __launch_bounds__(256) void k_norm_h(
    const float* __restrict__ hs, const float* __restrict__ w,
    unsigned int* __restrict__ normed_h2, float* __restrict__ bmax_arr)
{
    const int row = blockIdx.x;
    const int tid = threadIdx.x;
    const size_t S4 = NELEM / 4;  // shard stride in f32x4 units
    const f32x4* __restrict__ base =
        reinterpret_cast<const f32x4*>(hs) + (size_t)row * (HIDDEN_ / 4);
    const f32x4* __restrict__ w4 = reinterpret_cast<const f32x4*>(w);

    f32x4 sv[4];
    float ss = 0.f;
#pragma unroll
    for (int j = 0; j < 4; ++j) {
        const size_t idx = (size_t)tid + j * 256;
        f32x4 a = __builtin_nontemporal_load(&base[idx]);
        f32x4 b = __builtin_nontemporal_load(&base[idx + S4]);
        f32x4 c = __builtin_nontemporal_load(&base[idx + 2 * S4]);
        f32x4 d = __builtin_nontemporal_load(&base[idx + 3 * S4]);
        f32x4 s = (a + b) + (c + d);
        sv[j] = s;
        ss += s.x * s.x + s.y * s.y + s.z * s.z + s.w * s.w;
    }

    __shared__ float red[4];
#pragma unroll
    for (int off = 32; off > 0; off >>= 1) ss += __shfl_down(ss, off, 64);
    const int wave = tid >> 6;
    if ((tid & 63) == 0) red[wave] = ss;
    __syncthreads();
    ss = red[0] + red[1] + red[2] + red[3];
    const float inv = rsqrtf(ss * (1.0f / HIDDEN_) + EPS_);

    uint2* __restrict__ out =
        reinterpret_cast<uint2*>(normed_h2) + (size_t)row * (HIDDEN_ / 4);
    float am = 0.f;
#pragma unroll
    for (int j = 0; j < 4; ++j) {
        const size_t idx = (size_t)tid + j * 256;
        f32x4 wv = w4[idx];
        f32x4 s = sv[j];
        f32x4 o = s * inv * wv;
        uint2 p;
        p.x = pack_half2(o.x, o.y);
        p.y = pack_half2(o.z, o.w);
        out[idx] = p;
        am = fmaxf(am, fmaxf(fmaxf(fabsf(o.x), fabsf(o.y)),
                             fmaxf(fabsf(o.z), fabsf(o.w))));
    }

    __shared__ float redm[4];
#pragma unroll
    for (int off = 32; off > 0; off >>= 1)
        am = fmaxf(am, __shfl_down(am, off, 64));
    if ((tid & 63) == 0) redm[wave] = am;
    __syncthreads();
    if (tid == 0)
        bmax_arr[row] = fmaxf(fmaxf(redm[0], redm[1]), fmaxf(redm[2], redm[3]));
}

// Tiny pass: reduce bmax[8192] -> scale. One block.
__global__ __launch_bounds__(256) void k_amax_scale(
    const float* __restrict__ bmax_arr, float* __restrict__ ws_scale,
    float* __restrict__ scale_out)
{
    const int tid = threadIdx.x;
    const f32x4* __restrict__ b4 = reinterpret_cast<const f32x4*>(bmax_arr);
    float am = 0.f;
#pragma unroll
    for (int j = 0; j < 8; ++j) {  // 256 thr * 8 * 4 = 8192
        f32x4 v = b4[tid + j * 256];
        am = fmaxf(am, fmaxf(fmaxf(v.x, v.y), fmaxf(v.z, v.w)));
    }
    __shared__ float red[4];
#pragma unroll
    for (int off = 32; off > 0; off >>= 1)
        am = fmaxf(am, __shfl_down(am, off, 64));
    if ((tid & 63) == 0) red[tid >> 6] = am;
    __syncthreads();
    if (tid == 0) {
        am = fmaxf(fmaxf(red[0], red[1]), fmaxf(red[2], red[3]));
        const float scale = fmaxf(am, 1e-12f) / FP8MAX_;
        ws_scale[0] = scale;
        scale_out[0] = scale;
    }
}

// Pass 2: fp16 normed -> scale+clip -> fp32 q (nontemporal stores).
__global__ __launch_bounds__(256) void k_quant_h(
    const unsigned int* __restrict__ normed_h2,
    const float* __restrict__ ws_scale, float* __restrict__ q_out)
{
    const float invs = 1.0f / ws_scale[0];
    const size_t n8 = NELEM / 8;
    const u32x4* __restrict__ src = reinterpret_cast<const u32x4*>(normed_h2);
    f32x4* __restrict__ dst = reinterpret_cast<f32x4*>(q_out);
    const size_t stride = (size_t)gridDim.x * blockDim.x;
    for (size_t i = (size_t)blockIdx.x * blockDim.x + threadIdx.x; i < n8;
         i += stride) {
        u32x4 u = src[i];
        unsigned int u0 = u.x, u1 = u.y, u2 = u.z, u3 = u.w;
        float2 f0 = __half22float2(*reinterpret_cast<const __half2*>(&u0));
        float2 f1 = __half22float2(*reinterpret_cast<const __half2*>(&u1));
        float2 f2 = __half22float2(*reinterpret_cast<const __half2*>(&u2));
        float2 f3 = __half22float2(*reinterpret_cast<const __half2*>(&u3));
        f32x4 a, b;
        a.x = fminf(fmaxf(f0.x * invs, -FP8MAX_), FP8MAX_);
        a.y = fminf(fmaxf(f0.y * invs, -FP8MAX_), FP8MAX_);
        a.z = fminf(fmaxf(f1.x * invs, -FP8MAX_), FP8MAX_);
        a.w = fminf(fmaxf(f1.y * invs, -FP8MAX_), FP8MAX_);
        b.x = fminf(fmaxf(f2.x * invs, -FP8MAX_), FP8MAX_);
        b.y = fminf(fmaxf(f2.y * invs, -FP8MAX_), FP8MAX_);
        b.z = fminf(fmaxf(f3.x * invs, -FP8MAX_), FP8MAX_);
        b.w = fminf(fmaxf(f3.y * invs, -FP8MAX_), FP8MAX_);
        __builtin_nontemporal_store(a, &dst[i * 2]);
        __builtin_nontemporal_store(b, &dst[i * 2 + 1]);
    }
}

// ---------------- fallback: fp32 staged in d_out (needs no big ws) ----------

__global__ __launch_bounds__(256) void k_fused_norm_f(
    const float* __restrict__ hs, const float* __restrict__ w,
    float* __restrict__ normed, float* __restrict__ bmax_arr)
{
    const int row = blockIdx.x;
    const int tid = threadIdx.x;
    const size_t S4 = NELEM / 4;
    const f32x4* __restrict__ base =
        reinterpret_cast<const f32x4*>(hs) + (size_t)row * (HIDDEN_ / 4);
    const f32x4* __restrict__ w4 = reinterpret_cast<const f32x4*>(w);
    f32x4 sv[4];
    float ss = 0.f;
#pragma unroll
    for (int j = 0; j < 4; ++j) {
        const size_t idx = (size_t)tid + j * 256;
        f32x4 a = base[idx];
        f32x4 b = base[idx + S4];
        f32x4 c = base[idx + 2 * S4];
        f32x4 d = base[idx + 3 * S4];
        f32x4 s = (a + b) + (c + d);
        sv[j] = s;
        ss += s.x * s.x + s.y * s.y + s.z * s.z + s.w * s.w;
    }
    __shared__ float red[4];
#pragma unroll
    for (int off = 32; off > 0; off >>= 1) ss += __shfl_down(ss, off, 64);
    const int wave = tid >> 6;
    if ((tid & 63) == 0) red[wave] = ss;
    __syncthreads();
    ss = red[0] + red[1] + red[2] + red[3];
    const float inv = rsqrtf(ss * (1.0f / HIDDEN_) + EPS_);
    f32x4* __restrict__ out =
        reinterpret_cast<f32x4*>(normed) + (size_t)row * (HIDDEN_ / 4);
    float am = 0.f;
#pragma unroll
    for (int j = 0; j < 4; ++j) {
        const size_t idx = (size_t)tid + j * 256;
        f32x4 wv = w4[idx];
        f32x4 o = sv[j] * inv * wv;
        out[idx] = o;
        am = fmaxf(am, fmaxf(fmaxf(fabsf(o.x), fabsf(o.y)),
                             fmaxf(fabsf(o.z), fabsf(o.w))));
    }
    __shared__ float redm[4];
#pragma unroll
    for (int off = 32; off > 0; off >>= 1)
        am = fmaxf(am, __shfl_down(am, off, 64));
    if ((tid & 63) == 0) redm[wave] = am;
    __syncthreads();
    if (tid == 0)
        bmax_arr[row] = fmaxf(fmaxf(redm[0], redm[1]), fmaxf(redm[2], redm[3]));
}

__global__ __launch_bounds__(256) void k_quant_f(
    float* __restrict__ data, const float* __restrict__ ws_scale)
{
    const float invs = 1.0f / ws_scale[0];
    const size_t n4 = NELEM / 4;
    f32x4* __restrict__ d4 = reinterpret_cast<f32x4*>(data);
    const size_t stride = (size_t)gridDim.x * blockDim.x;
    for (size_t i = (size_t)blockIdx.x * blockDim.x + threadIdx.x; i < n4;
         i += stride) {
        f32x4 v = d4[i];
        v.x = fminf(fmaxf(v.x * invs, -FP8MAX_), FP8MAX_);
        v.y = fminf(fmaxf(v.y * invs, -FP8MAX_), FP8MAX_);
        v.z = fminf(fmaxf(v.z * invs, -FP8MAX_), FP8MAX_);
        v.w = fminf(fmaxf(v.w * invs, -FP8MAX_), FP8MAX_);
        d4[i] = v;
    }
}

extern "C" void kernel_launch(void* const* d_in, const int* in_sizes, int n_in,
                              void* d_out, int out_size, void* d_ws, size_t ws_size,
                              hipStream_t stream) {
    const float* hs = (const float*)d_in[0];   // [TP, TOKENS, HIDDEN]
    // d_in[1] = residual: unused by the reference computation
    const float* w  = (const float*)d_in[2];   // [HIDDEN]
    float* out = (float*)d_out;                // [N] q values + [1] scale
    float* scale_out = out + NELEM;

    float* ws_scale = (float*)((char*)d_ws + WS_SCALE_OFF);
    float* bmax_arr = (float*)((char*)d_ws + WS_BMAX_OFF);

    if (ws_size >= WS_NEEDED) {
        unsigned int* normed_h2 = (unsigned int*)((char*)d_ws + WS_H16_OFF);
        k_norm_h<<<TOKENS_, 256, 0, stream>>>(hs, w, normed_h2, bmax_arr);
        k_amax_scale<<<1, 256, 0, stream>>>(bmax_arr, ws_scale, scale_out);
        k_quant_h<<<2048, 256, 0, stream>>>(normed_h2, ws_scale, out);
    } else {
        // fallback: stage fp32 normed in d_out, quantize in place
        k_fused_norm_f<<<TOKENS_, 256, 0, stream>>>(hs, w, out, bmax_arr);
        k_amax_scale<<<1, 256, 0, stream>>>(bmax_arr, ws_scale, scale_out);
        k_quant_f<<<2048, 256, 0, stream>>>(out, ws_scale);
    }
}